// Round 1
// baseline (726.480 us; speedup 1.0000x reference)
//
#include <hip/hip_runtime.h>
#include <math.h>

#define BB 4096
#define DD 2048
#define CC 10000
#define KK 10
#define NT 256
#define EE 8   // DD / NT elements per thread

// ---------------- Kernel 1: per-row top-K (excluding true class) ----------------
__global__ __launch_bounds__(NT) void topk_kernel(const float* __restrict__ logits,
                                                  const int* __restrict__ y,
                                                  int* __restrict__ topk) {
    __shared__ __align__(16) float s_log[CC];
    __shared__ float s_wval[4];
    __shared__ int   s_widx[4];
    const int b = blockIdx.x;
    const int tid = threadIdx.x;

    // stage row into LDS (float4 coalesced: 2500 float4)
    const float4* row4 = (const float4*)(logits + (size_t)b * CC);
    float4* s4 = (float4*)s_log;
    for (int i = tid; i < CC / 4; i += NT) s4[i] = row4[i];
    __syncthreads();
    if (tid == 0) s_log[y[b]] = -1e9f;
    __syncthreads();

    for (int k = 0; k < KK; ++k) {
        float best = -3.0e38f;
        int bidx = 0x7fffffff;
        for (int i = tid; i < CC; i += NT) {
            float v = s_log[i];
            if (v > best) { best = v; bidx = i; }
        }
        // wave (64-lane) argmax reduce, tie-break lower index
        #pragma unroll
        for (int off = 32; off > 0; off >>= 1) {
            float ov = __shfl_down(best, off, 64);
            int   oi = __shfl_down(bidx, off, 64);
            if (ov > best || (ov == best && oi < bidx)) { best = ov; bidx = oi; }
        }
        const int wave = tid >> 6;
        if ((tid & 63) == 0) { s_wval[wave] = best; s_widx[wave] = bidx; }
        __syncthreads();
        if (tid == 0) {
            float bv = s_wval[0]; int bi = s_widx[0];
            #pragma unroll
            for (int w = 1; w < 4; ++w) {
                if (s_wval[w] > bv || (s_wval[w] == bv && s_widx[w] < bi)) {
                    bv = s_wval[w]; bi = s_widx[w];
                }
            }
            topk[b * KK + k] = bi;
            s_log[bi] = -1e9f;   // remove winner for next round
        }
        __syncthreads();
    }
}

// ---------------- block reduction helpers ----------------
__device__ __forceinline__ void phase_reduce10(float (&v)[KK], int tid, float (*s_red)[KK]) {
    const int lane = tid & 63, wave = tid >> 6;
    #pragma unroll
    for (int j = 0; j < KK; ++j) {
        float x = v[j];
        #pragma unroll
        for (int off = 32; off > 0; off >>= 1) x += __shfl_down(x, off, 64);
        if (lane == 0) s_red[wave][j] = x;
    }
    __syncthreads();
    #pragma unroll
    for (int j = 0; j < KK; ++j)
        v[j] = s_red[0][j] + s_red[1][j] + s_red[2][j] + s_red[3][j];
    __syncthreads();
}

__device__ __forceinline__ float phase_reduce1(float x, int tid, float* s1) {
    const int lane = tid & 63, wave = tid >> 6;
    #pragma unroll
    for (int off = 32; off > 0; off >>= 1) x += __shfl_down(x, off, 64);
    if (lane == 0) s1[wave] = x;
    __syncthreads();
    x = s1[0] + s1[1] + s1[2] + s1[3];
    __syncthreads();
    return x;
}

// ---------------- Kernel 2: QR-free CARROT augmentation ----------------
__global__ __launch_bounds__(NT) void aug_kernel(const float* __restrict__ z,
                                                 const int* __restrict__ y,
                                                 const float* __restrict__ W,
                                                 const float* __restrict__ noise,
                                                 const int* __restrict__ topk,
                                                 float* __restrict__ out,
                                                 int write_tail) {
    __shared__ float s_red[4][KK];
    __shared__ float s1[4];
    const int b = blockIdx.x;
    const int tid = threadIdx.x;

    const size_t zoff = (size_t)b * DD;
    // my 8 elements: d = 4*tid + e (e<4) and d = 1024 + 4*tid + (e-4)
    float4 z_a = ((const float4*)(z + zoff))[tid];
    float4 z_b = ((const float4*)(z + zoff + 1024))[tid];
    float4 n_a = ((const float4*)(noise + zoff))[tid];
    float4 n_b = ((const float4*)(noise + zoff + 1024))[tid];
    float zr[EE] = {z_a.x, z_a.y, z_a.z, z_a.w, z_b.x, z_b.y, z_b.z, z_b.w};
    float nr[EE] = {n_a.x, n_a.y, n_a.z, n_a.w, n_b.x, n_b.y, n_b.z, n_b.w};

    const int yb = y[b];
    const size_t wyoff = (size_t)yb * DD;
    float4 wy_a = ((const float4*)(W + wyoff))[tid];
    float4 wy_b = ((const float4*)(W + wyoff + 1024))[tid];
    float wy[EE] = {wy_a.x, wy_a.y, wy_a.z, wy_a.w, wy_b.x, wy_b.y, wy_b.z, wy_b.w};

    // A rows in registers: a[k][e] = w_y[d] - w_k[d]
    float a[KK][EE];
    #pragma unroll
    for (int k = 0; k < KK; ++k) {
        const size_t wo = (size_t)topk[b * KK + k] * DD;
        float4 wa = ((const float4*)(W + wo))[tid];
        float4 wb = ((const float4*)(W + wo + 1024))[tid];
        a[k][0] = wy[0] - wa.x; a[k][1] = wy[1] - wa.y;
        a[k][2] = wy[2] - wa.z; a[k][3] = wy[3] - wa.w;
        a[k][4] = wy[4] - wb.x; a[k][5] = wy[5] - wb.y;
        a[k][6] = wy[6] - wb.z; a[k][7] = wy[7] - wb.w;
    }

    // margins = A . z  (before orthonormalization)
    float m[KK];
    #pragma unroll
    for (int k = 0; k < KK; ++k) {
        float s = 0.f;
        #pragma unroll
        for (int e = 0; e < EE; ++e) s += a[k][e] * zr[e];
        m[k] = s;
    }
    phase_reduce10(m, tid, s_red);

    // CGS2 orthonormalization of the K rows (in place -> Q)
    unsigned keepmask = 0u;
    #pragma unroll
    for (int k = 0; k < KK; ++k) {
        #pragma unroll
        for (int pass = 0; pass < 2; ++pass) {
            if (k > 0) {
                float c[KK];
                #pragma unroll
                for (int j = 0; j < KK; ++j) {
                    float s = 0.f;
                    if (j < k) {
                        #pragma unroll
                        for (int e = 0; e < EE; ++e) s += a[j][e] * a[k][e];
                    }
                    c[j] = s;
                }
                phase_reduce10(c, tid, s_red);
                #pragma unroll
                for (int j = 0; j < KK; ++j) {
                    if (j < k) {
                        #pragma unroll
                        for (int e = 0; e < EE; ++e) a[k][e] -= c[j] * a[j][e];
                    }
                }
            }
        }
        float nn = 0.f;
        #pragma unroll
        for (int e = 0; e < EE; ++e) nn += a[k][e] * a[k][e];
        nn = phase_reduce1(nn, tid, s1);
        const float nrm = sqrtf(nn);
        const bool kp = nrm > 1e-6f;          // |R_kk| > QR_RANK_EPS
        if (kp) keepmask |= (1u << k);
        const float inv = kp ? 1.0f / nrm : 0.0f; // dropped column -> zeroed (== Qm)
        #pragma unroll
        for (int e = 0; e < EE; ++e) a[k][e] *= inv;
    }

    // alpha: all columns kept => pn2 clamps to EPS for every k (see theory)
    const float pn2  = 1e-8f;
    const float logt = 2.9957323f;            // float32(log(1/0.05))
    const float denomf = 2.0f * pn2 * logt + 1e-8f;
    float amin = 3.0e38f;
    #pragma unroll
    for (int k = 0; k < KK; ++k) {
        float sl = fmaxf(m[k], 0.0f);         // GAMMA = 0
        float al = (sl * sl) / denomf;
        amin = fminf(amin, al);
    }
    const bool valid = (keepmask != 0u) && (amin > 0.0f) && isfinite(amin);
    const float scale = valid ? sqrtf(fmaxf(amin, 0.0f)) : 0.0f;

    // epsN = noise - Q (Q^T noise);  z_aug = z + scale * epsN
    float cn[KK];
    #pragma unroll
    for (int r = 0; r < KK; ++r) {
        float s = 0.f;
        #pragma unroll
        for (int e = 0; e < EE; ++e) s += nr[e] * a[r][e];
        cn[r] = s;
    }
    phase_reduce10(cn, tid, s_red);

    float o[EE];
    #pragma unroll
    for (int e = 0; e < EE; ++e) {
        float proj = 0.f;
        #pragma unroll
        for (int r = 0; r < KK; ++r) proj += cn[r] * a[r][e];
        o[e] = zr[e] + scale * (nr[e] - proj);
    }
    float4 o0 = {o[0], o[1], o[2], o[3]};
    float4 o1 = {o[4], o[5], o[6], o[7]};
    ((float4*)(out + zoff))[tid] = o0;
    ((float4*)(out + zoff + 1024))[tid] = o1;

    if (write_tail && tid == 0) {
        out[(size_t)BB * DD + b] = (float)yb;                 // y passthrough
        out[(size_t)BB * DD + BB + b] = valid ? 1.0f : 0.0f;  // valid flag
    }
}

extern "C" void kernel_launch(void* const* d_in, const int* in_sizes, int n_in,
                              void* d_out, int out_size, void* d_ws, size_t ws_size,
                              hipStream_t stream) {
    const float* z      = (const float*)d_in[0];
    const int*   y      = (const int*)d_in[1];
    const float* logits = (const float*)d_in[2];
    const float* W      = (const float*)d_in[3];
    const float* noise  = (const float*)d_in[4];
    float* out = (float*)d_out;
    int* topk = (int*)d_ws;   // BB*KK ints

    topk_kernel<<<BB, NT, 0, stream>>>(logits, y, topk);
    const int write_tail = (out_size >= BB * DD + 2 * BB) ? 1 : 0;
    aug_kernel<<<BB, NT, 0, stream>>>(z, y, W, noise, topk, out, write_tail);
}

// Round 2
// 588.880 us; speedup vs baseline: 1.2337x; 1.2337x over previous
//
#include <hip/hip_runtime.h>
#include <math.h>

#define BB 4096
#define DD 2048
#define CC 10000
#define KK 10
#define NT 256
#define EE 8      // DD / NT elements per thread
#define NW 4      // waves per block
#define NF4 2500  // CC / 4
#define TRI(k) ((k)*((k)+1)/2)

// Single fused kernel: per-sample block (4096 blocks x 256 threads).
// Phase 1: top-10 confusing classes from registers (logits row in 10 float4/thread).
// Phase 2: A = w_y - w_k rows in registers; ONE reduction phase for
//          G = A A^T (55), margins m = A z (10), v = A noise (10);
//          redundant in-register Cholesky solve G c = v (projector = A^T G^-1 A,
//          identical to Qm Qm^T of the reference QR in the full-rank case;
//          chol diag == |R_kk| so the 1e-6 rank threshold maps exactly);
//          pn2 clamps to EPS=1e-8 always (fp32 residual ~1e-14 < EPS).
__global__ __launch_bounds__(NT, 2) void fused_kernel(
    const float* __restrict__ z, const int* __restrict__ y,
    const float* __restrict__ logits, const float* __restrict__ W,
    const float* __restrict__ noise, float* __restrict__ out, int write_tail)
{
    __shared__ float s_wv[NW];
    __shared__ int   s_wi[NW];
    __shared__ int   s_top[KK];
    __shared__ int   s_win;
    __shared__ float s_part[NW][80];   // 75 used

    const int b = blockIdx.x, tid = threadIdx.x;
    const int lane = tid & 63, wave = tid >> 6;
    const int yb = y[b];

    // ---------------- phase 1: top-K (exclude true class) ----------------
    float4 lg[10];
    const float4* lrow = (const float4*)(logits + (size_t)b * CC);
    #pragma unroll
    for (int j = 0; j < 10; ++j) {
        const int i4 = tid + 256 * j;
        if (i4 < NF4) lg[j] = lrow[i4];
        else          lg[j] = make_float4(-3e38f, -3e38f, -3e38f, -3e38f);
    }
    #pragma unroll
    for (int j = 0; j < 10; ++j) {           // mask true class
        const int rel = yb - 4 * (tid + 256 * j);
        if (rel == 0) lg[j].x = -3e38f;
        else if (rel == 1) lg[j].y = -3e38f;
        else if (rel == 2) lg[j].z = -3e38f;
        else if (rel == 3) lg[j].w = -3e38f;
    }

    float lbest; int lbidx;
    auto rescan = [&]() {
        lbest = -3.1e38f; lbidx = 0x7fffffff;
        #pragma unroll
        for (int j = 0; j < 10; ++j) {
            const int base = 4 * (tid + 256 * j);
            if (lg[j].x > lbest) { lbest = lg[j].x; lbidx = base + 0; }
            if (lg[j].y > lbest) { lbest = lg[j].y; lbidx = base + 1; }
            if (lg[j].z > lbest) { lbest = lg[j].z; lbidx = base + 2; }
            if (lg[j].w > lbest) { lbest = lg[j].w; lbidx = base + 3; }
        }
    };
    rescan();

    for (int r = 0; r < KK; ++r) {
        float bv = lbest; int bi = lbidx;
        #pragma unroll
        for (int off = 32; off > 0; off >>= 1) {
            const float ov = __shfl_down(bv, off, 64);
            const int   oi = __shfl_down(bi, off, 64);
            if (ov > bv || (ov == bv && oi < bi)) { bv = ov; bi = oi; }
        }
        if (lane == 0) { s_wv[wave] = bv; s_wi[wave] = bi; }
        __syncthreads();
        if (tid == 0) {
            float v0 = s_wv[0]; int i0 = s_wi[0];
            #pragma unroll
            for (int w = 1; w < NW; ++w)
                if (s_wv[w] > v0 || (s_wv[w] == v0 && s_wi[w] < i0)) { v0 = s_wv[w]; i0 = s_wi[w]; }
            s_top[r] = i0; s_win = i0;
        }
        __syncthreads();
        const int win = s_win;
        if (lbidx == win) {                   // owner removes + rescans (registers only)
            const int i4 = win >> 2;
            const int jw = (i4 - tid) >> 8;   // which float4 slot
            const int cw = win & 3;
            #pragma unroll
            for (int j = 0; j < 10; ++j) if (j == jw) {
                if (cw == 0) lg[j].x = -3e38f;
                else if (cw == 1) lg[j].y = -3e38f;
                else if (cw == 2) lg[j].z = -3e38f;
                else lg[j].w = -3e38f;
            }
            rescan();
        }
    }

    // ---------------- phase 2: augmentation ----------------
    const size_t zoff = (size_t)b * DD;
    const float4 z0 = ((const float4*)(z + zoff))[tid];
    const float4 z1 = ((const float4*)(z + zoff + 1024))[tid];
    const float4 n0 = ((const float4*)(noise + zoff))[tid];
    const float4 n1 = ((const float4*)(noise + zoff + 1024))[tid];
    const float zr[EE] = {z0.x, z0.y, z0.z, z0.w, z1.x, z1.y, z1.z, z1.w};
    const float nr[EE] = {n0.x, n0.y, n0.z, n0.w, n1.x, n1.y, n1.z, n1.w};

    const size_t wyo = (size_t)yb * DD;
    const float4 wy0 = ((const float4*)(W + wyo))[tid];
    const float4 wy1 = ((const float4*)(W + wyo + 1024))[tid];
    const float wy[EE] = {wy0.x, wy0.y, wy0.z, wy0.w, wy1.x, wy1.y, wy1.z, wy1.w};

    float a[KK][EE];
    #pragma unroll
    for (int k = 0; k < KK; ++k) {
        const size_t wo = (size_t)s_top[k] * DD;
        const float4 wa = ((const float4*)(W + wo))[tid];
        const float4 wb = ((const float4*)(W + wo + 1024))[tid];
        a[k][0] = wy[0] - wa.x; a[k][1] = wy[1] - wa.y;
        a[k][2] = wy[2] - wa.z; a[k][3] = wy[3] - wa.w;
        a[k][4] = wy[4] - wb.x; a[k][5] = wy[5] - wb.y;
        a[k][6] = wy[6] - wb.z; a[k][7] = wy[7] - wb.w;
    }

    // acc[0..54] = G upper-tri (G(j,k), j<=k at TRI(k)+j); [55..64] = m; [65..74] = v
    float acc[75];
    #pragma unroll
    for (int t = 0; t < 75; ++t) acc[t] = 0.0f;
    #pragma unroll
    for (int e = 0; e < EE; ++e) {
        #pragma unroll
        for (int k = 0; k < KK; ++k) {
            acc[55 + k] += a[k][e] * zr[e];
            acc[65 + k] += a[k][e] * nr[e];
            #pragma unroll
            for (int j = 0; j <= k; ++j)
                acc[TRI(k) + j] += a[j][e] * a[k][e];
        }
    }
    // ONE reduction phase for all 75 scalars
    #pragma unroll
    for (int t = 0; t < 75; ++t) {
        float x = acc[t];
        #pragma unroll
        for (int off = 32; off > 0; off >>= 1) x += __shfl_down(x, off, 64);
        if (lane == 0) s_part[wave][t] = x;
    }
    __syncthreads();
    #pragma unroll
    for (int t = 0; t < 75; ++t)
        acc[t] = s_part[0][t] + s_part[1][t] + s_part[2][t] + s_part[3][t];

    // in-place Cholesky G = L L^T (redundant per thread; fully unrolled)
    float dinv[KK];
    unsigned keepmask = 0u;
    #pragma unroll
    for (int k = 0; k < KK; ++k) {
        float s = acc[TRI(k) + k];
        #pragma unroll
        for (int j = 0; j < KK; ++j) if (j < k) { const float l = acc[TRI(k) + j]; s -= l * l; }
        const float dkk = sqrtf(fmaxf(s, 0.0f));
        const bool kp = dkk > 1e-6f;          // == |R_kk| > QR_RANK_EPS
        if (kp) keepmask |= (1u << k);
        dinv[k] = kp ? 1.0f / dkk : 0.0f;
        acc[TRI(k) + k] = dkk;
        #pragma unroll
        for (int i = 0; i < KK; ++i) if (i > k) {
            float t2 = acc[TRI(i) + k];
            #pragma unroll
            for (int j = 0; j < KK; ++j) if (j < k) t2 -= acc[TRI(i) + j] * acc[TRI(k) + j];
            acc[TRI(i) + k] = t2 * dinv[k];
        }
    }
    // solve G c = v : forward L w = v, then back L^T c = w (dropped pivots -> 0)
    float cvec[KK];
    #pragma unroll
    for (int i = 0; i < KK; ++i) {
        float s = acc[65 + i];
        #pragma unroll
        for (int j = 0; j < KK; ++j) if (j < i) s -= acc[TRI(i) + j] * cvec[j];
        cvec[i] = s * dinv[i];
    }
    #pragma unroll
    for (int i = KK - 1; i >= 0; --i) {
        float s = cvec[i];
        #pragma unroll
        for (int j = 0; j < KK; ++j) if (j > i) s -= acc[TRI(j) + i] * cvec[j];
        cvec[i] = s * dinv[i];
    }

    // alpha (pn2 clamped to EPS for every k — see header comment)
    const float denomf = 6.9914645e-8f;       // 2*EPS*log(20) + EPS in fp32
    float amin = 3.0e38f;
    #pragma unroll
    for (int k = 0; k < KK; ++k) {
        const float sl = fmaxf(acc[55 + k], 0.0f);   // GAMMA = 0
        amin = fminf(amin, sl * sl / denomf);
    }
    const bool valid = (keepmask != 0u) && (amin > 0.0f) && isfinite(amin);
    const float scale = valid ? sqrtf(amin) : 0.0f;

    // z_aug = z + scale * (noise - A^T c)
    float o[EE];
    #pragma unroll
    for (int e = 0; e < EE; ++e) {
        float proj = 0.0f;
        #pragma unroll
        for (int k = 0; k < KK; ++k) proj += cvec[k] * a[k][e];
        o[e] = zr[e] + scale * (nr[e] - proj);
    }
    const float4 o0 = {o[0], o[1], o[2], o[3]};
    const float4 o1 = {o[4], o[5], o[6], o[7]};
    ((float4*)(out + zoff))[tid] = o0;
    ((float4*)(out + zoff + 1024))[tid] = o1;

    if (write_tail && tid == 0) {
        out[(size_t)BB * DD + b] = (float)yb;
        out[(size_t)BB * DD + BB + b] = valid ? 1.0f : 0.0f;
    }
}

extern "C" void kernel_launch(void* const* d_in, const int* in_sizes, int n_in,
                              void* d_out, int out_size, void* d_ws, size_t ws_size,
                              hipStream_t stream) {
    const float* z      = (const float*)d_in[0];
    const int*   y      = (const int*)d_in[1];
    const float* logits = (const float*)d_in[2];
    const float* W      = (const float*)d_in[3];
    const float* noise  = (const float*)d_in[4];
    float* out = (float*)d_out;

    const int write_tail = (out_size >= BB * DD + 2 * BB) ? 1 : 0;
    fused_kernel<<<BB, NT, 0, stream>>>(z, y, logits, W, noise, out, write_tail);
}

// Round 3
// 477.424 us; speedup vs baseline: 1.5217x; 1.2335x over previous
//
#include <hip/hip_runtime.h>
#include <math.h>

#define BB 4096
#define DD 2048
#define CC 10000
#define KK 10
#define NT 256
#define NW 4
#define NF4 2500  // CC / 4
#define TRI(k) ((k)*((k)+1)/2)

// ---------------- Kernel 1: top-10 SET per row (order irrelevant downstream) ----
// Wave-local: each wave finds top-10 of its 2560-elem slice with shuffle-only
// argmax rounds (no barriers); wave 0 then picks top-10 of the 40 candidates.
__global__ __launch_bounds__(NT, 6) void topk_kernel(
    const float* __restrict__ logits, const int* __restrict__ y,
    int* __restrict__ topk)
{
    __shared__ float s_cv[NW * KK];
    __shared__ int   s_ci[NW * KK];

    const int b = blockIdx.x, tid = threadIdx.x;
    const int lane = tid & 63, wave = tid >> 6;
    const int yb = y[b];

    float4 lg[10];
    const float4* lrow = (const float4*)(logits + (size_t)b * CC);
    #pragma unroll
    for (int j = 0; j < 10; ++j) {
        const int i4 = tid + 256 * j;
        if (i4 < NF4) lg[j] = lrow[i4];
        else          lg[j] = make_float4(-3e38f, -3e38f, -3e38f, -3e38f);
    }
    #pragma unroll
    for (int j = 0; j < 10; ++j) {        // mask true class
        const int rel = yb - 4 * (tid + 256 * j);
        if (rel == 0) lg[j].x = -3e38f;
        else if (rel == 1) lg[j].y = -3e38f;
        else if (rel == 2) lg[j].z = -3e38f;
        else if (rel == 3) lg[j].w = -3e38f;
    }

    float lbest; int lbidx;
    auto rescan = [&]() {
        lbest = -3.1e38f; lbidx = 0x7fffffff;
        #pragma unroll
        for (int j = 0; j < 10; ++j) {
            const int base = 4 * (tid + 256 * j);
            if (lg[j].x > lbest) { lbest = lg[j].x; lbidx = base + 0; }
            if (lg[j].y > lbest) { lbest = lg[j].y; lbidx = base + 1; }
            if (lg[j].z > lbest) { lbest = lg[j].z; lbidx = base + 2; }
            if (lg[j].w > lbest) { lbest = lg[j].w; lbidx = base + 3; }
        }
    };
    rescan();

    // 10 wave-local rounds, no barriers
    for (int r = 0; r < KK; ++r) {
        float bv = lbest; int bi = lbidx;
        #pragma unroll
        for (int off = 32; off > 0; off >>= 1) {
            const float ov = __shfl_down(bv, off, 64);
            const int   oi = __shfl_down(bi, off, 64);
            if (ov > bv || (ov == bv && oi < bi)) { bv = ov; bi = oi; }
        }
        bv = __shfl(bv, 0, 64);
        bi = __shfl(bi, 0, 64);
        if (lane == 0) { s_cv[wave * KK + r] = bv; s_ci[wave * KK + r] = bi; }
        if (lbidx == bi) { // owner invalidates its element and rescans registers
            const int jw = ((bi >> 2) - tid) >> 8;
            const int cw = bi & 3;
            #pragma unroll
            for (int j = 0; j < 10; ++j) if (j == jw) {
                if (cw == 0) lg[j].x = -3e38f;
                else if (cw == 1) lg[j].y = -3e38f;
                else if (cw == 2) lg[j].z = -3e38f;
                else lg[j].w = -3e38f;
            }
            rescan();
        }
    }
    __syncthreads();

    if (wave == 0) { // select top-10 of the 40 wave candidates
        float cv = (lane < NW * KK) ? s_cv[lane] : -3.1e38f;
        int   ci = (lane < NW * KK) ? s_ci[lane] : 0x7fffffff;
        for (int r = 0; r < KK; ++r) {
            float bv = cv; int bi = ci;
            #pragma unroll
            for (int off = 32; off > 0; off >>= 1) {
                const float ov = __shfl_down(bv, off, 64);
                const int   oi = __shfl_down(bi, off, 64);
                if (ov > bv || (ov == bv && oi < bi)) { bv = ov; bi = oi; }
            }
            bi = __shfl(bi, 0, 64);
            if (lane == 0) topk[b * KK + r] = bi;
            if (ci == bi) cv = -3.1e38f;   // remove winner
        }
    }
}

// ---------------- Kernel 2: Gram/Cholesky augmentation, two-pass over D ------
// Pass 1: accumulate G = A A^T (55), m = A z (10), v = A noise (10) without
// keeping A resident (a[k] rebuilt per float4 chunk). One block-wide reduce.
// Wave 0 does Cholesky solve G c = v (chol diag == |R_kk| so the 1e-6 rank
// threshold maps exactly; pn2 clamps to EPS=1e-8 — fp32 residual ~1e-14).
// Pass 2: re-gather W chunks (L1/L2-hot) and write z + scale*(noise - A^T c).
__global__ __launch_bounds__(NT, 3) void aug_kernel(
    const float* __restrict__ z, const int* __restrict__ y,
    const float* __restrict__ W, const float* __restrict__ noise,
    const int* __restrict__ topk, float* __restrict__ out, int write_tail)
{
    __shared__ float s_part[NW][80];   // 75 used
    __shared__ float s_sol[16];        // cvec[10], scale, valid

    const int b = blockIdx.x, tid = threadIdx.x;
    const int lane = tid & 63, wave = tid >> 6;
    const int yb = y[b];

    int kidx[KK];
    #pragma unroll
    for (int k = 0; k < KK; ++k) kidx[k] = topk[b * KK + k];

    const size_t zoff = (size_t)b * DD;
    const float4 z0 = ((const float4*)(z + zoff))[tid];
    const float4 z1 = ((const float4*)(z + zoff + 1024))[tid];
    const float4 n0 = ((const float4*)(noise + zoff))[tid];
    const float4 n1 = ((const float4*)(noise + zoff + 1024))[tid];

    float acc[75];
    #pragma unroll
    for (int t = 0; t < 75; ++t) acc[t] = 0.0f;

    const size_t wyo = (size_t)yb * DD;
    #pragma unroll
    for (int c = 0; c < 2; ++c) {
        const size_t coff = (size_t)c * 1024;
        const float4 wy4 = ((const float4*)(W + wyo + coff))[tid];
        float4 a4[KK];
        #pragma unroll
        for (int k = 0; k < KK; ++k) {
            const float4 wk4 = ((const float4*)(W + (size_t)kidx[k] * DD + coff))[tid];
            a4[k].x = wy4.x - wk4.x; a4[k].y = wy4.y - wk4.y;
            a4[k].z = wy4.z - wk4.z; a4[k].w = wy4.w - wk4.w;
        }
        const float4 zc = c ? z1 : z0;
        const float4 nc = c ? n1 : n0;
        const float ze[4] = {zc.x, zc.y, zc.z, zc.w};
        const float ne[4] = {nc.x, nc.y, nc.z, nc.w};
        #pragma unroll
        for (int e = 0; e < 4; ++e) {
            float ak[KK];
            #pragma unroll
            for (int k = 0; k < KK; ++k)
                ak[k] = (e == 0) ? a4[k].x : (e == 1) ? a4[k].y : (e == 2) ? a4[k].z : a4[k].w;
            #pragma unroll
            for (int k = 0; k < KK; ++k) {
                acc[55 + k] += ak[k] * ze[e];
                acc[65 + k] += ak[k] * ne[e];
                #pragma unroll
                for (int j = 0; j <= k; ++j)
                    acc[TRI(k) + j] += ak[j] * ak[k];
            }
        }
    }

    // block reduce all 75 scalars (one phase)
    #pragma unroll
    for (int t = 0; t < 75; ++t) {
        float x = acc[t];
        #pragma unroll
        for (int off = 32; off > 0; off >>= 1) x += __shfl_down(x, off, 64);
        if (lane == 0) s_part[wave][t] = x;
    }
    __syncthreads();

    if (wave == 0) {   // Cholesky + triangular solves, redundant across wave 0 only
        float g[75];
        #pragma unroll
        for (int t = 0; t < 75; ++t)
            g[t] = s_part[0][t] + s_part[1][t] + s_part[2][t] + s_part[3][t];

        float dinv[KK];
        unsigned keepmask = 0u;
        #pragma unroll
        for (int k = 0; k < KK; ++k) {
            float s = g[TRI(k) + k];
            #pragma unroll
            for (int j = 0; j < KK; ++j) if (j < k) { const float l = g[TRI(k) + j]; s -= l * l; }
            const float dkk = sqrtf(fmaxf(s, 0.0f));
            const bool kp = dkk > 1e-6f;
            if (kp) keepmask |= (1u << k);
            dinv[k] = kp ? 1.0f / dkk : 0.0f;
            g[TRI(k) + k] = dkk;
            #pragma unroll
            for (int i = 0; i < KK; ++i) if (i > k) {
                float t2 = g[TRI(i) + k];
                #pragma unroll
                for (int j = 0; j < KK; ++j) if (j < k) t2 -= g[TRI(i) + j] * g[TRI(k) + j];
                g[TRI(i) + k] = t2 * dinv[k];
            }
        }
        float cvec[KK];
        #pragma unroll
        for (int i = 0; i < KK; ++i) {
            float s = g[65 + i];
            #pragma unroll
            for (int j = 0; j < KK; ++j) if (j < i) s -= g[TRI(i) + j] * cvec[j];
            cvec[i] = s * dinv[i];
        }
        #pragma unroll
        for (int i = KK - 1; i >= 0; --i) {
            float s = cvec[i];
            #pragma unroll
            for (int j = 0; j < KK; ++j) if (j > i) s -= g[TRI(j) + i] * cvec[j];
            cvec[i] = s * dinv[i];
        }
        const float denomf = 6.9914645e-8f;   // 2*EPS*log(20) + EPS (fp32)
        float amin = 3.0e38f;
        #pragma unroll
        for (int k = 0; k < KK; ++k) {
            const float sl = fmaxf(g[55 + k], 0.0f);   // GAMMA = 0
            amin = fminf(amin, sl * sl / denomf);
        }
        const bool valid = (keepmask != 0u) && (amin > 0.0f) && isfinite(amin);
        const float scale = valid ? sqrtf(amin) : 0.0f;
        if (lane == 0) {
            #pragma unroll
            for (int k = 0; k < KK; ++k) s_sol[k] = cvec[k];
            s_sol[10] = scale;
            s_sol[11] = valid ? 1.0f : 0.0f;
        }
    }
    __syncthreads();

    float cvec[KK];
    #pragma unroll
    for (int k = 0; k < KK; ++k) cvec[k] = s_sol[k];
    const float scale = s_sol[10];

    // pass 2: re-gather W chunks (cache-hot), project, write out
    #pragma unroll
    for (int c = 0; c < 2; ++c) {
        const size_t coff = (size_t)c * 1024;
        const float4 wy4 = ((const float4*)(W + wyo + coff))[tid];
        float4 proj = make_float4(0.f, 0.f, 0.f, 0.f);
        float csum = 0.f;
        #pragma unroll
        for (int k = 0; k < KK; ++k) {
            const float4 wk4 = ((const float4*)(W + (size_t)kidx[k] * DD + coff))[tid];
            proj.x -= cvec[k] * wk4.x; proj.y -= cvec[k] * wk4.y;
            proj.z -= cvec[k] * wk4.z; proj.w -= cvec[k] * wk4.w;
            csum += cvec[k];
        }
        proj.x += csum * wy4.x; proj.y += csum * wy4.y;
        proj.z += csum * wy4.z; proj.w += csum * wy4.w;
        const float4 zc = c ? z1 : z0;
        const float4 nc = c ? n1 : n0;
        float4 o;
        o.x = zc.x + scale * (nc.x - proj.x);
        o.y = zc.y + scale * (nc.y - proj.y);
        o.z = zc.z + scale * (nc.z - proj.z);
        o.w = zc.w + scale * (nc.w - proj.w);
        ((float4*)(out + zoff + coff))[tid] = o;
    }

    if (write_tail && tid == 0) {
        out[(size_t)BB * DD + b] = (float)yb;
        out[(size_t)BB * DD + BB + b] = s_sol[11];
    }
}

extern "C" void kernel_launch(void* const* d_in, const int* in_sizes, int n_in,
                              void* d_out, int out_size, void* d_ws, size_t ws_size,
                              hipStream_t stream) {
    const float* z      = (const float*)d_in[0];
    const int*   y      = (const int*)d_in[1];
    const float* logits = (const float*)d_in[2];
    const float* W      = (const float*)d_in[3];
    const float* noise  = (const float*)d_in[4];
    float* out = (float*)d_out;
    int* topk = (int*)d_ws;   // BB*KK ints

    topk_kernel<<<BB, NT, 0, stream>>>(logits, y, topk);
    const int write_tail = (out_size >= BB * DD + 2 * BB) ? 1 : 0;
    aug_kernel<<<BB, NT, 0, stream>>>(z, y, W, noise, topk, out, write_tail);
}